// Round 1
// baseline (2300.809 us; speedup 1.0000x reference)
//
#include <hip/hip_runtime.h>
#include <hip/hip_bf16.h>
#include <cstddef>

// Problem constants (QueryMambaOp)
constexpr int BATCH = 2;
constexpr int SEQLEN = 2048;
constexpr int DM = 768;        // d_model
constexpr int DI = 1536;       // d_inner
constexpr int DS = 16;         // d_state
constexpr int XZC = 3072;      // 2*d_inner (xz row stride)
constexpr int XP = 80;         // dt_rank + 2*d_state
constexpr int M = BATCH * SEQLEN;  // 4096 rows

__device__ __forceinline__ float siluf(float x) {
    return x / (1.f + __expf(-x));
}
__device__ __forceinline__ float softplusf(float x) {
    return (x > 20.f) ? x : log1pf(__expf(x));
}

// C[m,n] = epilogue( sum_k A[m,k] * W[n,k] (+ bias[n]) )
// EPI 0: none   EPI 1: softplus(acc+bias)   EPI 2: Y[m,n]*silu(acc+bias)
// Requires: M multiple of 64, K multiple of 16. N arbitrary (guarded).
template<int EPI>
__global__ __launch_bounds__(256)
void gemm_nt(const float* __restrict__ A, int lda,
             const float* __restrict__ W, int ldw,
             float* __restrict__ C, int ldc,
             int N, int K,
             const float* __restrict__ bias,
             const float* __restrict__ Y, int ldy)
{
    __shared__ float As[16][64];
    __shared__ float Bs[16][64];
    const int tid = threadIdx.x;
    const int tx = tid & 15;       // output col group
    const int ty = tid >> 4;       // output row group
    const int m0 = blockIdx.y * 64;
    const int n0 = blockIdx.x * 64;
    const int lr = tid >> 2;       // staging row 0..63
    const int lk = (tid & 3) * 4;  // staging k offset 0,4,8,12

    float acc[4][4];
#pragma unroll
    for (int i = 0; i < 4; ++i)
#pragma unroll
        for (int j = 0; j < 4; ++j) acc[i][j] = 0.f;

    for (int kt = 0; kt < K; kt += 16) {
        float4 av = *(const float4*)(A + (size_t)(m0 + lr) * lda + kt + lk);
        float4 wv = make_float4(0.f, 0.f, 0.f, 0.f);
        if (n0 + lr < N)
            wv = *(const float4*)(W + (size_t)(n0 + lr) * ldw + kt + lk);
        __syncthreads();
        As[lk + 0][lr] = av.x; As[lk + 1][lr] = av.y;
        As[lk + 2][lr] = av.z; As[lk + 3][lr] = av.w;
        Bs[lk + 0][lr] = wv.x; Bs[lk + 1][lr] = wv.y;
        Bs[lk + 2][lr] = wv.z; Bs[lk + 3][lr] = wv.w;
        __syncthreads();
#pragma unroll
        for (int kk = 0; kk < 16; ++kk) {
            float4 a = *(const float4*)&As[kk][ty * 4];
            float4 b = *(const float4*)&Bs[kk][tx * 4];
            float ar[4] = {a.x, a.y, a.z, a.w};
            float br[4] = {b.x, b.y, b.z, b.w};
#pragma unroll
            for (int i = 0; i < 4; ++i)
#pragma unroll
                for (int j = 0; j < 4; ++j)
                    acc[i][j] = fmaf(ar[i], br[j], acc[i][j]);
        }
    }

#pragma unroll
    for (int i = 0; i < 4; ++i) {
        const int row = m0 + ty * 4 + i;
#pragma unroll
        for (int j = 0; j < 4; ++j) {
            const int col = n0 + tx * 4 + j;
            if (col < N) {
                float v = acc[i][j];
                if (EPI >= 1) v += bias[col];
                if (EPI == 1) v = softplusf(v);
                float outv;
                if (EPI == 2)
                    outv = Y[(size_t)row * ldy + col] * siluf(v);
                else
                    outv = v;
                C[(size_t)row * ldc + col] = outv;
            }
        }
    }
}

// xs[row,d] = silu( sum_k cw[d,k]*x[row+k-3, d] + cb[d] )   (causal within each batch)
__global__ __launch_bounds__(256)
void conv_silu(const float* __restrict__ xz, const float* __restrict__ cw,
               const float* __restrict__ cb, float* __restrict__ xs)
{
    int idx = blockIdx.x * blockDim.x + threadIdx.x;
    if (idx >= M * DI) return;
    int d = idx % DI;
    int row = idx / DI;       // b*L + l
    int l = row % SEQLEN;
    const float* base = xz + (size_t)row * XZC + d;
    float acc = cb[d];
    float w0 = cw[d * 4 + 0], w1 = cw[d * 4 + 1], w2 = cw[d * 4 + 2], w3 = cw[d * 4 + 3];
    // x_conv[l] = sum_k w[k] * x[l + k - 3]
    if (l >= 3) acc = fmaf(w0, base[-(ptrdiff_t)3 * XZC], acc);
    if (l >= 2) acc = fmaf(w1, base[-(ptrdiff_t)2 * XZC], acc);
    if (l >= 1) acc = fmaf(w2, base[-(ptrdiff_t)1 * XZC], acc);
    acc = fmaf(w3, base[0], acc);
    xs[(size_t)row * DI + d] = siluf(acc);
}

// Selective scan. One 16-lane subgroup per (b, d) channel; lane = state index n.
// Epilogue fused: y = (sum_n h*C + xs*D) * silu(z);  y written into xz x-half.
__global__ __launch_bounds__(256)
void scan_kernel(float* xz,   // read z-half, write y into x-half
                 const float* __restrict__ xs, const float* __restrict__ dt,
                 const float* __restrict__ xdbl, const float* __restrict__ A_log,
                 const float* __restrict__ Dvec)
{
    const int blk = blockIdx.x;                 // 0 .. B*DI/16-1  (192)
    const int b = blk / (DI / 16);
    const int dblk = blk % (DI / 16);
    const int n = threadIdx.x & 15;
    const int d = dblk * 16 + (threadIdx.x >> 4);

    const float Adn = -__expf(A_log[d * DS + n]);
    const float Dd = Dvec[d];
    float h = 0.f;

    const size_t rbase = (size_t)b * SEQLEN;
    const float* dtp = dt + d;
    const float* xsp = xs + d;
    const float* bp = xdbl + 48 + n;
    const float* cp = xdbl + 64 + n;

    for (int l = 0; l < SEQLEN; ++l) {
        const size_t row = rbase + l;
        float dtv = dtp[row * DI];
        float xv  = xsp[row * DI];
        float Bv  = bp[row * XP];
        float Cv  = cp[row * XP];
        float dA = __expf(dtv * Adn);
        h = fmaf(dA, h, (dtv * xv) * Bv);
        float p = h * Cv;
        p += __shfl_xor(p, 8, 16);
        p += __shfl_xor(p, 4, 16);
        p += __shfl_xor(p, 2, 16);
        p += __shfl_xor(p, 1, 16);
        if (n == 0) {
            float zv = xz[row * XZC + DI + d];
            float y = (p + xv * Dd) * siluf(zv);
            xz[row * XZC + d] = y;
        }
    }
}

extern "C" void kernel_launch(void* const* d_in, const int* in_sizes, int n_in,
                              void* d_out, int out_size, void* d_ws, size_t ws_size,
                              hipStream_t stream)
{
    const float* hidden    = (const float*)d_in[0];
    const float* query     = (const float*)d_in[1];
    const float* in_proj_w = (const float*)d_in[2];
    const float* conv_w    = (const float*)d_in[3];
    const float* conv_b    = (const float*)d_in[4];
    const float* x_proj_w  = (const float*)d_in[5];
    const float* dt_proj_w = (const float*)d_in[6];
    const float* dt_proj_b = (const float*)d_in[7];
    const float* A_log     = (const float*)d_in[8];
    const float* Dvec      = (const float*)d_in[9];
    const float* query_w   = (const float*)d_in[10];
    const float* query_b   = (const float*)d_in[11];
    const float* out_proj_w= (const float*)d_in[12];
    float* out = (float*)d_out;

    float* ws = (float*)d_ws;
    float* xz   = ws;                              // M x 3072 (x | z), later y | yg
    float* xs   = xz   + (size_t)M * XZC;          // M x 1536
    float* dtb  = xs   + (size_t)M * DI;           // M x 1536
    float* xdbl = dtb  + (size_t)M * DI;           // M x 80

    dim3 blk(256);

    // 1. in_proj: xz = hidden @ in_proj_w^T    (4096 x 3072, K=768)
    gemm_nt<0><<<dim3(XZC / 64, M / 64), blk, 0, stream>>>(
        hidden, DM, in_proj_w, DM, xz, XZC, XZC, DM, nullptr, nullptr, 0);

    // 2. causal depthwise conv + silu -> xs
    conv_silu<<<(M * DI + 255) / 256, blk, 0, stream>>>(xz, conv_w, conv_b, xs);

    // 3. x_proj: xdbl = xs @ x_proj_w^T        (4096 x 80, K=1536)
    gemm_nt<0><<<dim3((XP + 63) / 64, M / 64), blk, 0, stream>>>(
        xs, DI, x_proj_w, DI, xdbl, XP, XP, DI, nullptr, nullptr, 0);

    // 4. dt_proj + softplus: dt = softplus(xdbl[:, :48] @ dt_proj_w^T + b)  (4096x1536, K=48)
    gemm_nt<1><<<dim3(DI / 64, M / 64), blk, 0, stream>>>(
        xdbl, XP, dt_proj_w, 48, dtb, DI, DI, 48, dt_proj_b, nullptr, 0);

    // 5. selective scan (+ D skip, * silu(z)) -> y into xz[:, :1536]
    scan_kernel<<<BATCH * DI / 16, blk, 0, stream>>>(xz, xs, dtb, xdbl, A_log, Dvec);

    // 6. query proj fused gate: yg = y * silu(query @ query_w^T + qb) -> xz[:, 1536:]
    gemm_nt<2><<<dim3(DI / 64, M / 64), blk, 0, stream>>>(
        query, DM, query_w, DM, xz + DI, XZC, DI, DM, query_b, xz, XZC);

    // 7. out_proj: out = yg @ out_proj_w^T     (4096 x 768, K=1536)
    gemm_nt<0><<<dim3(DM / 64, M / 64), blk, 0, stream>>>(
        xz + DI, XZC, out_proj_w, DI, out, DM, DM, DI, nullptr, nullptr, 0);
}

// Round 2
// 897.524 us; speedup vs baseline: 2.5635x; 2.5635x over previous
//
#include <hip/hip_runtime.h>
#include <hip/hip_bf16.h>
#include <cstddef>

// Problem constants (QueryMambaOp)
constexpr int BATCH = 2;
constexpr int SEQLEN = 2048;
constexpr int DM = 768;        // d_model
constexpr int DI = 1536;       // d_inner
constexpr int DS = 16;         // d_state
constexpr int XZC = 3072;      // 2*d_inner (xz row stride)
constexpr int XP = 80;         // dt_rank + 2*d_state
constexpr int M = BATCH * SEQLEN;  // 4096 rows
constexpr int CH = 64;             // rows per scan chunk
constexpr int NC = SEQLEN / CH;    // 32 chunks

__device__ __forceinline__ float siluf(float x) {
    return x / (1.f + __expf(-x));
}
__device__ __forceinline__ float softplusf(float x) {
    return (x > 20.f) ? x : log1pf(__expf(x));
}

// C[m,n] = epilogue( sum_k A[m,k] * W[n,k] (+ bias[n]) )
// EPI 0: none   EPI 1: softplus(acc+bias)   EPI 2: Y[m,n]*silu(acc+bias)
template<int EPI>
__global__ __launch_bounds__(256)
void gemm_nt(const float* __restrict__ A, int lda,
             const float* __restrict__ W, int ldw,
             float* __restrict__ C, int ldc,
             int N, int K,
             const float* __restrict__ bias,
             const float* __restrict__ Y, int ldy)
{
    __shared__ float As[16][64];
    __shared__ float Bs[16][64];
    const int tid = threadIdx.x;
    const int tx = tid & 15;       // output col group
    const int ty = tid >> 4;       // output row group
    const int m0 = blockIdx.y * 64;
    const int n0 = blockIdx.x * 64;
    const int lr = tid >> 2;       // staging row 0..63
    const int lk = (tid & 3) * 4;  // staging k offset 0,4,8,12

    float acc[4][4];
#pragma unroll
    for (int i = 0; i < 4; ++i)
#pragma unroll
        for (int j = 0; j < 4; ++j) acc[i][j] = 0.f;

    for (int kt = 0; kt < K; kt += 16) {
        float4 av = *(const float4*)(A + (size_t)(m0 + lr) * lda + kt + lk);
        float4 wv = make_float4(0.f, 0.f, 0.f, 0.f);
        if (n0 + lr < N)
            wv = *(const float4*)(W + (size_t)(n0 + lr) * ldw + kt + lk);
        __syncthreads();
        As[lk + 0][lr] = av.x; As[lk + 1][lr] = av.y;
        As[lk + 2][lr] = av.z; As[lk + 3][lr] = av.w;
        Bs[lk + 0][lr] = wv.x; Bs[lk + 1][lr] = wv.y;
        Bs[lk + 2][lr] = wv.z; Bs[lk + 3][lr] = wv.w;
        __syncthreads();
#pragma unroll
        for (int kk = 0; kk < 16; ++kk) {
            float4 a = *(const float4*)&As[kk][ty * 4];
            float4 b = *(const float4*)&Bs[kk][tx * 4];
            float ar[4] = {a.x, a.y, a.z, a.w};
            float br[4] = {b.x, b.y, b.z, b.w};
#pragma unroll
            for (int i = 0; i < 4; ++i)
#pragma unroll
                for (int j = 0; j < 4; ++j)
                    acc[i][j] = fmaf(ar[i], br[j], acc[i][j]);
        }
    }

#pragma unroll
    for (int i = 0; i < 4; ++i) {
        const int row = m0 + ty * 4 + i;
#pragma unroll
        for (int j = 0; j < 4; ++j) {
            const int col = n0 + tx * 4 + j;
            if (col < N) {
                float v = acc[i][j];
                if (EPI >= 1) v += bias[col];
                if (EPI == 1) v = softplusf(v);
                float outv;
                if (EPI == 2)
                    outv = Y[(size_t)row * ldy + col] * siluf(v);
                else
                    outv = v;
                C[(size_t)row * ldc + col] = outv;
            }
        }
    }
}

// xs[row,d] = silu( sum_k cw[d,k]*x[row+k-3, d] + cb[d] )   (causal within each batch)
__global__ __launch_bounds__(256)
void conv_silu(const float* __restrict__ xz, const float* __restrict__ cw,
               const float* __restrict__ cb, float* __restrict__ xs)
{
    int idx = blockIdx.x * blockDim.x + threadIdx.x;
    if (idx >= M * DI) return;
    int d = idx % DI;
    int row = idx / DI;       // b*L + l
    int l = row % SEQLEN;
    const float* base = xz + (size_t)row * XZC + d;
    float acc = cb[d];
    float w0 = cw[d * 4 + 0], w1 = cw[d * 4 + 1], w2 = cw[d * 4 + 2], w3 = cw[d * 4 + 3];
    if (l >= 3) acc = fmaf(w0, base[-(ptrdiff_t)3 * XZC], acc);
    if (l >= 2) acc = fmaf(w1, base[-(ptrdiff_t)2 * XZC], acc);
    if (l >= 1) acc = fmaf(w2, base[-(ptrdiff_t)1 * XZC], acc);
    acc = fmaf(w3, base[0], acc);
    xs[(size_t)row * DI + d] = siluf(acc);
}

// ---- Chunk-parallel selective scan -----------------------------------------
// Transfer layout: trans[((b*NC + c)*DI + d)*DS + n] = {a, b} where
//   h_end(chunk) = a * h_start(chunk) + b
// Pass B overwrites .y with h_start(chunk).

// Pass A: per-chunk transfer coefficients. Thread = (d, state-quad).
__global__ __launch_bounds__(256)
void scan_chunk_a(const float* __restrict__ dt, const float* __restrict__ xs,
                  const float* __restrict__ xdbl, const float* __restrict__ A_log,
                  float2* __restrict__ trans)
{
    const int q = threadIdx.x & 3;        // state quad: n = 4q..4q+3
    const int dloc = threadIdx.x >> 2;    // 0..63
    const int d = blockIdx.x * 64 + dloc;
    const int c = blockIdx.y;
    const int b = blockIdx.z;
    const int n0 = q * 4;

    float An[4], a[4], bb[4];
#pragma unroll
    for (int k = 0; k < 4; ++k) {
        An[k] = -__expf(A_log[d * DS + n0 + k]);
        a[k] = 1.f; bb[k] = 0.f;
    }
    const size_t r0 = (size_t)b * SEQLEN + (size_t)c * CH;
    for (int l = 0; l < CH; ++l) {
        const size_t row = r0 + l;
        float dtv = dt[row * DI + d];
        float xv  = xs[row * DI + d];
        float dtx = dtv * xv;
#pragma unroll
        for (int k = 0; k < 4; ++k) {
            float Bv = xdbl[row * XP + 48 + n0 + k];
            float dA = __expf(dtv * An[k]);
            a[k] *= dA;
            bb[k] = fmaf(dA, bb[k], dtx * Bv);
        }
    }
    float2* tp = trans + ((size_t)(b * NC + c) * DI + d) * DS + n0;
#pragma unroll
    for (int k = 0; k < 4; ++k) tp[k] = make_float2(a[k], bb[k]);
}

// Pass B: sequential combine over chunks; writes h_start into .y.
__global__ __launch_bounds__(256)
void scan_chunk_b(float2* __restrict__ trans)
{
    const int idx = blockIdx.x * 256 + threadIdx.x;   // (b, d*DS+n) flat
    const int b = idx / (DI * DS);
    const int dn = idx % (DI * DS);
    float2* tp = trans + (size_t)b * NC * DI * DS + dn;
    float h = 0.f;
    for (int c = 0; c < NC; ++c) {
        float2 ab = tp[(size_t)c * DI * DS];
        tp[(size_t)c * DI * DS].y = h;   // h_start for chunk c
        h = fmaf(ab.x, h, ab.y);
    }
}

// Pass C: re-scan each chunk from h_start; fused epilogue
//   y = (sum_n h*C + xs*D) * silu(z), written into xz x-half.
__global__ __launch_bounds__(256)
void scan_chunk_c(float* xz, const float* __restrict__ xs,
                  const float* __restrict__ dt, const float* __restrict__ xdbl,
                  const float* __restrict__ A_log, const float* __restrict__ Dvec,
                  const float2* __restrict__ trans)
{
    const int q = threadIdx.x & 3;
    const int dloc = threadIdx.x >> 2;
    const int d = blockIdx.x * 64 + dloc;
    const int c = blockIdx.y;
    const int b = blockIdx.z;
    const int n0 = q * 4;

    float An[4], h[4];
    const float2* tp = trans + ((size_t)(b * NC + c) * DI + d) * DS + n0;
#pragma unroll
    for (int k = 0; k < 4; ++k) {
        An[k] = -__expf(A_log[d * DS + n0 + k]);
        h[k] = tp[k].y;
    }
    const float Dd = Dvec[d];
    const size_t r0 = (size_t)b * SEQLEN + (size_t)c * CH;
    for (int l = 0; l < CH; ++l) {
        const size_t row = r0 + l;
        float dtv = dt[row * DI + d];
        float xv  = xs[row * DI + d];
        float dtx = dtv * xv;
        float p = 0.f;
#pragma unroll
        for (int k = 0; k < 4; ++k) {
            float Bv = xdbl[row * XP + 48 + n0 + k];
            float Cv = xdbl[row * XP + 64 + n0 + k];
            float dA = __expf(dtv * An[k]);
            h[k] = fmaf(dA, h[k], dtx * Bv);
            p = fmaf(h[k], Cv, p);
        }
        p += __shfl_xor(p, 1, 4);
        p += __shfl_xor(p, 2, 4);
        if (q == 0) {
            float zv = xz[row * XZC + DI + d];
            xz[row * XZC + d] = (p + xv * Dd) * siluf(zv);
        }
    }
}

extern "C" void kernel_launch(void* const* d_in, const int* in_sizes, int n_in,
                              void* d_out, int out_size, void* d_ws, size_t ws_size,
                              hipStream_t stream)
{
    const float* hidden    = (const float*)d_in[0];
    const float* query     = (const float*)d_in[1];
    const float* in_proj_w = (const float*)d_in[2];
    const float* conv_w    = (const float*)d_in[3];
    const float* conv_b    = (const float*)d_in[4];
    const float* x_proj_w  = (const float*)d_in[5];
    const float* dt_proj_w = (const float*)d_in[6];
    const float* dt_proj_b = (const float*)d_in[7];
    const float* A_log     = (const float*)d_in[8];
    const float* Dvec      = (const float*)d_in[9];
    const float* query_w   = (const float*)d_in[10];
    const float* query_b   = (const float*)d_in[11];
    const float* out_proj_w= (const float*)d_in[12];
    float* out = (float*)d_out;

    float* ws = (float*)d_ws;
    float* xz   = ws;                              // M x 3072 (x | z), later y | yg
    float* xs   = xz   + (size_t)M * XZC;          // M x 1536
    float* dtb  = xs   + (size_t)M * DI;           // M x 1536
    float* xdbl = dtb  + (size_t)M * DI;           // M x 80
    float2* trans = (float2*)(xdbl + (size_t)M * XP);  // B*NC*DI*DS float2 (12.6 MB)

    dim3 blk(256);

    // 1. in_proj: xz = hidden @ in_proj_w^T    (4096 x 3072, K=768)
    gemm_nt<0><<<dim3(XZC / 64, M / 64), blk, 0, stream>>>(
        hidden, DM, in_proj_w, DM, xz, XZC, XZC, DM, nullptr, nullptr, 0);

    // 2. causal depthwise conv + silu -> xs
    conv_silu<<<(M * DI + 255) / 256, blk, 0, stream>>>(xz, conv_w, conv_b, xs);

    // 3. x_proj: xdbl = xs @ x_proj_w^T        (4096 x 80, K=1536)
    gemm_nt<0><<<dim3((XP + 63) / 64, M / 64), blk, 0, stream>>>(
        xs, DI, x_proj_w, DI, xdbl, XP, XP, DI, nullptr, nullptr, 0);

    // 4. dt_proj + softplus: dt = softplus(xdbl[:, :48] @ dt_proj_w^T + b)  (4096x1536, K=48)
    gemm_nt<1><<<dim3(DI / 64, M / 64), blk, 0, stream>>>(
        xdbl, XP, dt_proj_w, 48, dtb, DI, DI, 48, dt_proj_b, nullptr, 0);

    // 5. chunk-parallel selective scan (+ D skip, * silu(z)) -> y into xz[:, :1536]
    scan_chunk_a<<<dim3(DI / 64, NC, BATCH), blk, 0, stream>>>(dtb, xs, xdbl, A_log, trans);
    scan_chunk_b<<<(BATCH * DI * DS) / 256, blk, 0, stream>>>(trans);
    scan_chunk_c<<<dim3(DI / 64, NC, BATCH), blk, 0, stream>>>(xz, xs, dtb, xdbl, A_log, Dvec, trans);

    // 6. query proj fused gate: yg = y * silu(query @ query_w^T + qb) -> xz[:, 1536:]
    gemm_nt<2><<<dim3(DI / 64, M / 64), blk, 0, stream>>>(
        query, DM, query_w, DM, xz + DI, XZC, DI, DM, query_b, xz, XZC);

    // 7. out_proj: out = yg @ out_proj_w^T     (4096 x 768, K=1536)
    gemm_nt<0><<<dim3(DM / 64, M / 64), blk, 0, stream>>>(
        xz + DI, XZC, out_proj_w, DI, out, DM, DM, DI, nullptr, nullptr, 0);
}

// Round 3
// 449.985 us; speedup vs baseline: 5.1131x; 1.9946x over previous
//
#include <hip/hip_runtime.h>
#include <hip/hip_bf16.h>
#include <cstddef>
#include <cstdint>

// Problem constants (QueryMambaOp)
constexpr int BATCH = 2;
constexpr int SEQLEN = 2048;
constexpr int DM = 768;        // d_model
constexpr int DI = 1536;       // d_inner
constexpr int DS = 16;         // d_state
constexpr int XZC = 3072;      // 2*d_inner (xz row stride)
constexpr int XP = 80;         // dt_rank + 2*d_state
constexpr int M = BATCH * SEQLEN;  // 4096 rows
constexpr int CH = 64;             // rows per scan chunk
constexpr int NC = SEQLEN / CH;    // 32 chunks

typedef __attribute__((ext_vector_type(8))) short bf16x8;
typedef __attribute__((ext_vector_type(4))) float floatx4;

__device__ __forceinline__ float siluf(float x) {
    return x / (1.f + __expf(-x));
}
__device__ __forceinline__ float softplusf(float x) {
    return (x > 20.f) ? x : log1pf(__expf(x));
}
__device__ __forceinline__ unsigned short f2bf(float f) {
    unsigned int u = __builtin_bit_cast(unsigned int, f);
    u += 0x7fffu + ((u >> 16) & 1u);   // round-to-nearest-even
    return (unsigned short)(u >> 16);
}
__device__ __forceinline__ void load16_to_lds(const void* g, void* l) {
    __builtin_amdgcn_global_load_lds(
        (const __attribute__((address_space(1))) void*)g,
        (__attribute__((address_space(3))) void*)l, 16, 0, 0);
}

// float -> bf16 bits, 4 elems/thread
__global__ __launch_bounds__(256)
void cast_bf16(const float* __restrict__ in, unsigned short* __restrict__ o, int n4)
{
    int i = blockIdx.x * 256 + threadIdx.x;
    if (i >= n4) return;
    float4 v = ((const float4*)in)[i];
    union { unsigned short u[4]; uint2 w; } r;
    r.u[0] = f2bf(v.x); r.u[1] = f2bf(v.y); r.u[2] = f2bf(v.z); r.u[3] = f2bf(v.w);
    ((uint2*)o)[i] = r.w;
}

// ---- bf16 MFMA GEMM:  C[m,n] = epi( sum_k A[m,k]*W[n,k] ) ------------------
// 128x128 tile, 4 waves of 64x64, mfma_f32_16x16x32_bf16, BK=32.
// EPI 0: Cf[m*ldc+n] = acc (fp32)
// EPI 2: Cb[m*ldc+n] = bf16( Y[m*ldy+n] * silu(acc + bias[n]) )
// Requires M%128==0, N%128==0, K%32==0. A: MxK bf16 bits, W: NxK bf16 bits.
template<int EPI>
__global__ __launch_bounds__(256)
void gemm_bf16(const unsigned short* __restrict__ A, int lda,
               const unsigned short* __restrict__ W, int ldw,
               int K,
               float* __restrict__ Cf, unsigned short* __restrict__ Cb, int ldc,
               const float* __restrict__ bias,
               const float* __restrict__ Y, int ldy)
{
    __shared__ __align__(16) short Atile[128 * 32];
    __shared__ __align__(16) short Btile[128 * 32];
    const int tid = threadIdx.x;
    const int wave = tid >> 6;
    const int lane = tid & 63;
    const int m0 = blockIdx.y * 128;
    const int n0 = blockIdx.x * 128;
    const int wm = (wave >> 1) * 64;
    const int wn = (wave & 1) * 64;
    const int lrow = lane & 15;    // m (A) / n (B) / n (C)
    const int lq = lane >> 4;      // k-quad, and C row group

    floatx4 zero = {0.f, 0.f, 0.f, 0.f};
    floatx4 acc[4][4];
#pragma unroll
    for (int i = 0; i < 4; ++i)
#pragma unroll
        for (int j = 0; j < 4; ++j) acc[i][j] = zero;

    for (int kt = 0; kt < K; kt += 32) {
        __syncthreads();   // previous iteration done reading LDS
#pragma unroll
        for (int j = 0; j < 2; ++j) {
            int idx = (wave * 2 + j) * 64 + lane;   // 0..511, 16B chunk id
            int r = idx >> 2;
            int c = (idx & 3) * 8;
            load16_to_lds(A + (size_t)(m0 + r) * lda + kt + c,
                          Atile + (wave * 2 + j) * 512);
            load16_to_lds(W + (size_t)(n0 + r) * ldw + kt + c,
                          Btile + (wave * 2 + j) * 512);
        }
        __syncthreads();   // drains vmcnt(0): LDS tiles ready

        bf16x8 af[4], bf[4];
#pragma unroll
        for (int i = 0; i < 4; ++i)
            af[i] = *(const bf16x8*)&Atile[(wm + i * 16 + lrow) * 32 + lq * 8];
#pragma unroll
        for (int i = 0; i < 4; ++i)
            bf[i] = *(const bf16x8*)&Btile[(wn + i * 16 + lrow) * 32 + lq * 8];
#pragma unroll
        for (int mi = 0; mi < 4; ++mi)
#pragma unroll
            for (int ni = 0; ni < 4; ++ni)
                acc[mi][ni] = __builtin_amdgcn_mfma_f32_16x16x32_bf16(
                    af[mi], bf[ni], acc[mi][ni], 0, 0, 0);
    }

    // C/D layout: n = lane&15, m = (lane>>4)*4 + reg
#pragma unroll
    for (int mi = 0; mi < 4; ++mi) {
#pragma unroll
        for (int r = 0; r < 4; ++r) {
            const int m = m0 + wm + mi * 16 + lq * 4 + r;
#pragma unroll
            for (int ni = 0; ni < 4; ++ni) {
                const int n = n0 + wn + ni * 16 + lrow;
                float v = acc[mi][ni][r];
                if (EPI == 0) {
                    Cf[(size_t)m * ldc + n] = v;
                } else {
                    v += bias[n];
                    float g = Y[(size_t)m * ldy + n] * siluf(v);
                    Cb[(size_t)m * ldc + n] = f2bf(g);
                }
            }
        }
    }
}

// ---- fp32 tiled GEMM (kept for the small x_proj / dt_proj) -----------------
// EPI 0: none   EPI 1: softplus(acc+bias)
template<int EPI>
__global__ __launch_bounds__(256)
void gemm_nt(const float* __restrict__ A, int lda,
             const float* __restrict__ W, int ldw,
             float* __restrict__ C, int ldc,
             int N, int K,
             const float* __restrict__ bias)
{
    __shared__ float As[16][64];
    __shared__ float Bs[16][64];
    const int tid = threadIdx.x;
    const int tx = tid & 15;
    const int ty = tid >> 4;
    const int m0 = blockIdx.y * 64;
    const int n0 = blockIdx.x * 64;
    const int lr = tid >> 2;
    const int lk = (tid & 3) * 4;

    float acc[4][4];
#pragma unroll
    for (int i = 0; i < 4; ++i)
#pragma unroll
        for (int j = 0; j < 4; ++j) acc[i][j] = 0.f;

    for (int kt = 0; kt < K; kt += 16) {
        float4 av = *(const float4*)(A + (size_t)(m0 + lr) * lda + kt + lk);
        float4 wv = make_float4(0.f, 0.f, 0.f, 0.f);
        if (n0 + lr < N)
            wv = *(const float4*)(W + (size_t)(n0 + lr) * ldw + kt + lk);
        __syncthreads();
        As[lk + 0][lr] = av.x; As[lk + 1][lr] = av.y;
        As[lk + 2][lr] = av.z; As[lk + 3][lr] = av.w;
        Bs[lk + 0][lr] = wv.x; Bs[lk + 1][lr] = wv.y;
        Bs[lk + 2][lr] = wv.z; Bs[lk + 3][lr] = wv.w;
        __syncthreads();
#pragma unroll
        for (int kk = 0; kk < 16; ++kk) {
            float4 a = *(const float4*)&As[kk][ty * 4];
            float4 b = *(const float4*)&Bs[kk][tx * 4];
            float ar[4] = {a.x, a.y, a.z, a.w};
            float br[4] = {b.x, b.y, b.z, b.w};
#pragma unroll
            for (int i = 0; i < 4; ++i)
#pragma unroll
                for (int j = 0; j < 4; ++j)
                    acc[i][j] = fmaf(ar[i], br[j], acc[i][j]);
        }
    }

#pragma unroll
    for (int i = 0; i < 4; ++i) {
        const int row = m0 + ty * 4 + i;
#pragma unroll
        for (int j = 0; j < 4; ++j) {
            const int col = n0 + tx * 4 + j;
            if (col < N) {
                float v = acc[i][j];
                if (EPI == 1) v = softplusf(v + bias[col]);
                C[(size_t)row * ldc + col] = v;
            }
        }
    }
}

// xs[row,d] = silu( sum_k cw[d,k]*x[row+k-3, d] + cb[d] )
__global__ __launch_bounds__(256)
void conv_silu(const float* __restrict__ xz, const float* __restrict__ cw,
               const float* __restrict__ cb, float* __restrict__ xs)
{
    int idx = blockIdx.x * blockDim.x + threadIdx.x;
    if (idx >= M * DI) return;
    int d = idx % DI;
    int row = idx / DI;
    int l = row % SEQLEN;
    const float* base = xz + (size_t)row * XZC + d;
    float acc = cb[d];
    float w0 = cw[d * 4 + 0], w1 = cw[d * 4 + 1], w2 = cw[d * 4 + 2], w3 = cw[d * 4 + 3];
    if (l >= 3) acc = fmaf(w0, base[-(ptrdiff_t)3 * XZC], acc);
    if (l >= 2) acc = fmaf(w1, base[-(ptrdiff_t)2 * XZC], acc);
    if (l >= 1) acc = fmaf(w2, base[-(ptrdiff_t)1 * XZC], acc);
    acc = fmaf(w3, base[0], acc);
    xs[(size_t)row * DI + d] = siluf(acc);
}

// ---- Chunk-parallel selective scan -----------------------------------------
__global__ __launch_bounds__(256)
void scan_chunk_a(const float* __restrict__ dt, const float* __restrict__ xs,
                  const float* __restrict__ xdbl, const float* __restrict__ A_log,
                  float2* __restrict__ trans)
{
    const int q = threadIdx.x & 3;
    const int dloc = threadIdx.x >> 2;
    const int d = blockIdx.x * 64 + dloc;
    const int c = blockIdx.y;
    const int b = blockIdx.z;
    const int n0 = q * 4;

    float An[4], a[4], bb[4];
#pragma unroll
    for (int k = 0; k < 4; ++k) {
        An[k] = -__expf(A_log[d * DS + n0 + k]);
        a[k] = 1.f; bb[k] = 0.f;
    }
    const size_t r0 = (size_t)b * SEQLEN + (size_t)c * CH;
    for (int l = 0; l < CH; ++l) {
        const size_t row = r0 + l;
        float dtv = dt[row * DI + d];
        float xv  = xs[row * DI + d];
        float dtx = dtv * xv;
#pragma unroll
        for (int k = 0; k < 4; ++k) {
            float Bv = xdbl[row * XP + 48 + n0 + k];
            float dA = __expf(dtv * An[k]);
            a[k] *= dA;
            bb[k] = fmaf(dA, bb[k], dtx * Bv);
        }
    }
    float2* tp = trans + ((size_t)(b * NC + c) * DI + d) * DS + n0;
#pragma unroll
    for (int k = 0; k < 4; ++k) tp[k] = make_float2(a[k], bb[k]);
}

__global__ __launch_bounds__(256)
void scan_chunk_b(float2* __restrict__ trans)
{
    const int idx = blockIdx.x * 256 + threadIdx.x;
    const int b = idx / (DI * DS);
    const int dn = idx % (DI * DS);
    float2* tp = trans + (size_t)b * NC * DI * DS + dn;
    float h = 0.f;
    for (int c = 0; c < NC; ++c) {
        float2 ab = tp[(size_t)c * DI * DS];
        tp[(size_t)c * DI * DS].y = h;
        h = fmaf(ab.x, h, ab.y);
    }
}

__global__ __launch_bounds__(256)
void scan_chunk_c(float* xz, const float* __restrict__ xs,
                  const float* __restrict__ dt, const float* __restrict__ xdbl,
                  const float* __restrict__ A_log, const float* __restrict__ Dvec,
                  const float2* __restrict__ trans)
{
    const int q = threadIdx.x & 3;
    const int dloc = threadIdx.x >> 2;
    const int d = blockIdx.x * 64 + dloc;
    const int c = blockIdx.y;
    const int b = blockIdx.z;
    const int n0 = q * 4;

    float An[4], h[4];
    const float2* tp = trans + ((size_t)(b * NC + c) * DI + d) * DS + n0;
#pragma unroll
    for (int k = 0; k < 4; ++k) {
        An[k] = -__expf(A_log[d * DS + n0 + k]);
        h[k] = tp[k].y;
    }
    const float Dd = Dvec[d];
    const size_t r0 = (size_t)b * SEQLEN + (size_t)c * CH;
    for (int l = 0; l < CH; ++l) {
        const size_t row = r0 + l;
        float dtv = dt[row * DI + d];
        float xv  = xs[row * DI + d];
        float dtx = dtv * xv;
        float p = 0.f;
#pragma unroll
        for (int k = 0; k < 4; ++k) {
            float Bv = xdbl[row * XP + 48 + n0 + k];
            float Cv = xdbl[row * XP + 64 + n0 + k];
            float dA = __expf(dtv * An[k]);
            h[k] = fmaf(dA, h[k], dtx * Bv);
            p = fmaf(h[k], Cv, p);
        }
        p += __shfl_xor(p, 1, 4);
        p += __shfl_xor(p, 2, 4);
        if (q == 0) {
            float zv = xz[row * XZC + DI + d];
            xz[row * XZC + d] = (p + xv * Dd) * siluf(zv);
        }
    }
}

extern "C" void kernel_launch(void* const* d_in, const int* in_sizes, int n_in,
                              void* d_out, int out_size, void* d_ws, size_t ws_size,
                              hipStream_t stream)
{
    const float* hidden    = (const float*)d_in[0];
    const float* query     = (const float*)d_in[1];
    const float* in_proj_w = (const float*)d_in[2];
    const float* conv_w    = (const float*)d_in[3];
    const float* conv_b    = (const float*)d_in[4];
    const float* x_proj_w  = (const float*)d_in[5];
    const float* dt_proj_w = (const float*)d_in[6];
    const float* dt_proj_b = (const float*)d_in[7];
    const float* A_log     = (const float*)d_in[8];
    const float* Dvec      = (const float*)d_in[9];
    const float* query_w   = (const float*)d_in[10];
    const float* query_b   = (const float*)d_in[11];
    const float* out_proj_w= (const float*)d_in[12];
    float* out = (float*)d_out;

    char* p = (char*)d_ws;
    float* xz   = (float*)p;  p += (size_t)M * XZC * 4;       // 50.3 MB
    float* xs   = (float*)p;  p += (size_t)M * DI * 4;        // 25.2 MB
    float* dtb  = (float*)p;  p += (size_t)M * DI * 4;        // 25.2 MB
    float* xdbl = (float*)p;  p += (size_t)M * XP * 4;        // 1.3 MB
    float2* trans = (float2*)p; p += (size_t)BATCH * NC * DI * DS * 8;  // 12.6 MB
    unsigned short* hb  = (unsigned short*)p; p += (size_t)M * DM * 2;      // 6.3 MB
    unsigned short* qb  = (unsigned short*)p; p += (size_t)M * DM * 2;      // 6.3 MB
    unsigned short* ygb = (unsigned short*)p; p += (size_t)M * DI * 2;      // 12.6 MB
    unsigned short* wib = (unsigned short*)p; p += (size_t)XZC * DM * 2;    // 4.7 MB
    unsigned short* wqb = (unsigned short*)p; p += (size_t)DI * DM * 2;     // 2.4 MB
    unsigned short* wob = (unsigned short*)p; p += (size_t)DM * DI * 2;     // 2.4 MB

    dim3 blk(256);

    // 0. casts to bf16
    cast_bf16<<<(M * DM / 4 + 255) / 256, blk, 0, stream>>>(hidden, hb, M * DM / 4);
    cast_bf16<<<(XZC * DM / 4 + 255) / 256, blk, 0, stream>>>(in_proj_w, wib, XZC * DM / 4);
    cast_bf16<<<(M * DM / 4 + 255) / 256, blk, 0, stream>>>(query, qb, M * DM / 4);
    cast_bf16<<<(DI * DM / 4 + 255) / 256, blk, 0, stream>>>(query_w, wqb, DI * DM / 4);
    cast_bf16<<<(DM * DI / 4 + 255) / 256, blk, 0, stream>>>(out_proj_w, wob, DM * DI / 4);

    // 1. in_proj (bf16 MFMA): xz = hidden @ in_proj_w^T   (4096 x 3072, K=768)
    gemm_bf16<0><<<dim3(XZC / 128, M / 128), blk, 0, stream>>>(
        hb, DM, wib, DM, DM, xz, nullptr, XZC, nullptr, nullptr, 0);

    // 2. causal depthwise conv + silu -> xs
    conv_silu<<<(M * DI + 255) / 256, blk, 0, stream>>>(xz, conv_w, conv_b, xs);

    // 3. x_proj (fp32): xdbl = xs @ x_proj_w^T            (4096 x 80, K=1536)
    gemm_nt<0><<<dim3((XP + 63) / 64, M / 64), blk, 0, stream>>>(
        xs, DI, x_proj_w, DI, xdbl, XP, XP, DI, nullptr);

    // 4. dt_proj + softplus (fp32)                        (4096 x 1536, K=48)
    gemm_nt<1><<<dim3(DI / 64, M / 64), blk, 0, stream>>>(
        xdbl, XP, dt_proj_w, 48, dtb, DI, DI, 48, dt_proj_b);

    // 5. chunk-parallel selective scan -> y into xz[:, :1536]
    scan_chunk_a<<<dim3(DI / 64, NC, BATCH), blk, 0, stream>>>(dtb, xs, xdbl, A_log, trans);
    scan_chunk_b<<<(BATCH * DI * DS) / 256, blk, 0, stream>>>(trans);
    scan_chunk_c<<<dim3(DI / 64, NC, BATCH), blk, 0, stream>>>(xz, xs, dtb, xdbl, A_log, Dvec, trans);

    // 6. query gate (bf16 MFMA, EPI2): ygb = bf16( y * silu(query@query_w^T + qb) )
    gemm_bf16<2><<<dim3(DI / 128, M / 128), blk, 0, stream>>>(
        qb, DM, wqb, DM, DM, nullptr, ygb, DI, query_b, xz, XZC);

    // 7. out_proj (bf16 MFMA): out = ygb @ out_proj_w^T   (4096 x 768, K=1536)
    gemm_bf16<0><<<dim3(DM / 128, M / 128), blk, 0, stream>>>(
        ygb, DI, wob, DI, DI, out, nullptr, DM, nullptr, nullptr, 0);
}

// Round 5
// 389.330 us; speedup vs baseline: 5.9097x; 1.1558x over previous
//
#include <hip/hip_runtime.h>
#include <hip/hip_bf16.h>
#include <cstddef>
#include <cstdint>

// Problem constants (QueryMambaOp)
constexpr int BATCH = 2;
constexpr int SEQLEN = 2048;
constexpr int DM = 768;        // d_model
constexpr int DI = 1536;       // d_inner
constexpr int DS = 16;         // d_state
constexpr int XZC = 3072;      // 2*d_inner (xz row stride)
constexpr int XP = 80;         // dt_rank + 2*d_state
constexpr int M = BATCH * SEQLEN;  // 4096 rows
constexpr int CH = 64;             // rows per scan chunk
constexpr int NC = SEQLEN / CH;    // 32 chunks
constexpr int KS = 8;              // k-slices for split-K x_proj

typedef __attribute__((ext_vector_type(8))) short bf16x8;
typedef __attribute__((ext_vector_type(4))) float floatx4;

__device__ __forceinline__ float siluf(float x) {
    return x / (1.f + __expf(-x));
}
__device__ __forceinline__ float softplusf(float x) {
    return (x > 20.f) ? x : log1pf(__expf(x));
}
__device__ __forceinline__ unsigned short f2bf(float f) {
    unsigned int u = __builtin_bit_cast(unsigned int, f);
    u += 0x7fffu + ((u >> 16) & 1u);   // round-to-nearest-even
    return (unsigned short)(u >> 16);
}
__device__ __forceinline__ void load16_to_lds(const void* g, void* l) {
    __builtin_amdgcn_global_load_lds(
        (const __attribute__((address_space(1))) void*)g,
        (__attribute__((address_space(3))) void*)l, 16, 0, 0);
}
__device__ __forceinline__ void cast4(const float* in, unsigned short* o, int i) {
    float4 v = ((const float4*)in)[i];
    union { unsigned short u[4]; uint2 w; } r;
    r.u[0] = f2bf(v.x); r.u[1] = f2bf(v.y); r.u[2] = f2bf(v.z); r.u[3] = f2bf(v.w);
    ((uint2*)o)[i] = r.w;
}

// two equal-size casts in one launch (blockIdx.y selects)
__global__ __launch_bounds__(256)
void cast_bf16_2(const float* __restrict__ a, unsigned short* __restrict__ ao,
                 const float* __restrict__ b, unsigned short* __restrict__ bo, int n4)
{
    int i = blockIdx.x * 256 + threadIdx.x;
    if (i >= n4) return;
    if (blockIdx.y == 0) cast4(a, ao, i); else cast4(b, bo, i);
}

// three weight casts in one launch (flat index, if-chain)
__global__ __launch_bounds__(256)
void cast_bf16_3(const float* __restrict__ a, unsigned short* __restrict__ ao, int n0,
                 const float* __restrict__ b, unsigned short* __restrict__ bo, int n1,
                 const float* __restrict__ c, unsigned short* __restrict__ co, int n2)
{
    int i = blockIdx.x * 256 + threadIdx.x;
    if (i < n0) { cast4(a, ao, i); return; }
    i -= n0;
    if (i < n1) { cast4(b, bo, i); return; }
    i -= n1;
    if (i < n2) cast4(c, co, i);
}

// ---- bf16 MFMA GEMM:  C[m,n] = epi( sum_k A[m,k]*W[n,k] ) ------------------
// 128x128 tile, 4 waves of 64x64, mfma_f32_16x16x32_bf16, BK=32.
// EPI 0: Cf[m*ldc+n] = acc (fp32)
// EPI 2: Cb[m*ldc+n] = bf16( Y[m*ldy+n] * silu(acc + bias[n]) )
template<int EPI>
__global__ __launch_bounds__(256)
void gemm_bf16(const unsigned short* __restrict__ A, int lda,
               const unsigned short* __restrict__ W, int ldw,
               int K,
               float* __restrict__ Cf, unsigned short* __restrict__ Cb, int ldc,
               const float* __restrict__ bias,
               const float* __restrict__ Y, int ldy)
{
    __shared__ __align__(16) short Atile[128 * 32];
    __shared__ __align__(16) short Btile[128 * 32];
    const int tid = threadIdx.x;
    const int wave = tid >> 6;
    const int lane = tid & 63;
    const int m0 = blockIdx.y * 128;
    const int n0 = blockIdx.x * 128;
    const int wm = (wave >> 1) * 64;
    const int wn = (wave & 1) * 64;
    const int lrow = lane & 15;
    const int lq = lane >> 4;

    floatx4 zero = {0.f, 0.f, 0.f, 0.f};
    floatx4 acc[4][4];
#pragma unroll
    for (int i = 0; i < 4; ++i)
#pragma unroll
        for (int j = 0; j < 4; ++j) acc[i][j] = zero;

    for (int kt = 0; kt < K; kt += 32) {
        __syncthreads();
#pragma unroll
        for (int j = 0; j < 2; ++j) {
            int idx = (wave * 2 + j) * 64 + lane;
            int r = idx >> 2;
            int c = (idx & 3) * 8;
            load16_to_lds(A + (size_t)(m0 + r) * lda + kt + c,
                          Atile + (wave * 2 + j) * 512);
            load16_to_lds(W + (size_t)(n0 + r) * ldw + kt + c,
                          Btile + (wave * 2 + j) * 512);
        }
        __syncthreads();

        bf16x8 af[4], bf[4];
#pragma unroll
        for (int i = 0; i < 4; ++i)
            af[i] = *(const bf16x8*)&Atile[(wm + i * 16 + lrow) * 32 + lq * 8];
#pragma unroll
        for (int i = 0; i < 4; ++i)
            bf[i] = *(const bf16x8*)&Btile[(wn + i * 16 + lrow) * 32 + lq * 8];
#pragma unroll
        for (int mi = 0; mi < 4; ++mi)
#pragma unroll
            for (int ni = 0; ni < 4; ++ni)
                acc[mi][ni] = __builtin_amdgcn_mfma_f32_16x16x32_bf16(
                    af[mi], bf[ni], acc[mi][ni], 0, 0, 0);
    }

    // C/D layout: n = lane&15, m = (lane>>4)*4 + reg
#pragma unroll
    for (int mi = 0; mi < 4; ++mi) {
#pragma unroll
        for (int r = 0; r < 4; ++r) {
            const int m = m0 + wm + mi * 16 + lq * 4 + r;
#pragma unroll
            for (int ni = 0; ni < 4; ++ni) {
                const int n = n0 + wn + ni * 16 + lrow;
                float v = acc[mi][ni][r];
                if (EPI == 0) {
                    Cf[(size_t)m * ldc + n] = v;
                } else {
                    v += bias[n];
                    float g = Y[(size_t)m * ldy + n] * siluf(v);
                    Cb[(size_t)m * ldc + n] = f2bf(g);
                }
            }
        }
    }
}

// ---- fp32 tiled GEMM (small x_proj / dt_proj) ------------------------------
// EPI 0: plain store   EPI 1: softplus(acc+bias) store
// EPI 4: per-slice store C[z*M*ldc + row*ldc + col] (deterministic split-K)
template<int EPI>
__global__ __launch_bounds__(256)
void gemm_nt(const float* __restrict__ A, int lda,
             const float* __restrict__ W, int ldw,
             float* __restrict__ C, int ldc,
             int N, int K, int kchunk,
             const float* __restrict__ bias)
{
    __shared__ float As[16][64];
    __shared__ float Bs[16][64];
    const int tid = threadIdx.x;
    const int tx = tid & 15;
    const int ty = tid >> 4;
    const int m0 = blockIdx.y * 64;
    const int n0 = blockIdx.x * 64;
    const int lr = tid >> 2;
    const int lk = (tid & 3) * 4;

    float acc[4][4];
#pragma unroll
    for (int i = 0; i < 4; ++i)
#pragma unroll
        for (int j = 0; j < 4; ++j) acc[i][j] = 0.f;

    const int k0 = blockIdx.z * kchunk;
    const int kend = min(K, k0 + kchunk);
    for (int kt = k0; kt < kend; kt += 16) {
        float4 av = *(const float4*)(A + (size_t)(m0 + lr) * lda + kt + lk);
        float4 wv = make_float4(0.f, 0.f, 0.f, 0.f);
        if (n0 + lr < N)
            wv = *(const float4*)(W + (size_t)(n0 + lr) * ldw + kt + lk);
        __syncthreads();
        As[lk + 0][lr] = av.x; As[lk + 1][lr] = av.y;
        As[lk + 2][lr] = av.z; As[lk + 3][lr] = av.w;
        Bs[lk + 0][lr] = wv.x; Bs[lk + 1][lr] = wv.y;
        Bs[lk + 2][lr] = wv.z; Bs[lk + 3][lr] = wv.w;
        __syncthreads();
#pragma unroll
        for (int kk = 0; kk < 16; ++kk) {
            float4 a = *(const float4*)&As[kk][ty * 4];
            float4 b = *(const float4*)&Bs[kk][tx * 4];
            float ar[4] = {a.x, a.y, a.z, a.w};
            float br[4] = {b.x, b.y, b.z, b.w};
#pragma unroll
            for (int i = 0; i < 4; ++i)
#pragma unroll
                for (int j = 0; j < 4; ++j)
                    acc[i][j] = fmaf(ar[i], br[j], acc[i][j]);
        }
    }

    float* Cbase = (EPI == 4) ? C + (size_t)blockIdx.z * M * ldc : C;
#pragma unroll
    for (int i = 0; i < 4; ++i) {
        const int row = m0 + ty * 4 + i;
#pragma unroll
        for (int j = 0; j < 4; ++j) {
            const int col = n0 + tx * 4 + j;
            if (col < N) {
                float v = acc[i][j];
                if (EPI == 1) v = softplusf(v + bias[col]);
                Cbase[(size_t)row * ldc + col] = v;
            }
        }
    }
}

// sum 8 k-slice partials -> xdbl   (float4 over M*XP)
__global__ __launch_bounds__(256)
void reduce_xp(const float* __restrict__ part, float* __restrict__ xdbl, int n4)
{
    int i = blockIdx.x * 256 + threadIdx.x;
    if (i >= n4) return;
    float4 s = ((const float4*)part)[i];
#pragma unroll
    for (int z = 1; z < KS; ++z) {
        float4 v = ((const float4*)(part + (size_t)z * M * XP))[i];
        s.x += v.x; s.y += v.y; s.z += v.z; s.w += v.w;
    }
    ((float4*)xdbl)[i] = s;
}

// xs[row,d] = silu( sum_k cw[d,k]*x[row+k-3, d] + cb[d] )
__global__ __launch_bounds__(256)
void conv_silu(const float* __restrict__ xz, const float* __restrict__ cw,
               const float* __restrict__ cb, float* __restrict__ xs)
{
    int idx = blockIdx.x * blockDim.x + threadIdx.x;
    if (idx >= M * DI) return;
    int d = idx % DI;
    int row = idx / DI;
    int l = row % SEQLEN;
    const float* base = xz + (size_t)row * XZC + d;
    float acc = cb[d];
    float w0 = cw[d * 4 + 0], w1 = cw[d * 4 + 1], w2 = cw[d * 4 + 2], w3 = cw[d * 4 + 3];
    if (l >= 3) acc = fmaf(w0, base[-(ptrdiff_t)3 * XZC], acc);
    if (l >= 2) acc = fmaf(w1, base[-(ptrdiff_t)2 * XZC], acc);
    if (l >= 1) acc = fmaf(w2, base[-(ptrdiff_t)1 * XZC], acc);
    acc = fmaf(w3, base[0], acc);
    xs[(size_t)row * DI + d] = siluf(acc);
}

// ---- Chunk-parallel selective scan -----------------------------------------
__global__ __launch_bounds__(256)
void scan_chunk_a(const float* __restrict__ dt, const float* __restrict__ xs,
                  const float* __restrict__ xdbl, const float* __restrict__ A_log,
                  float2* __restrict__ trans)
{
    const int q = threadIdx.x & 3;
    const int dloc = threadIdx.x >> 2;
    const int d = blockIdx.x * 64 + dloc;
    const int c = blockIdx.y;
    const int b = blockIdx.z;
    const int n0 = q * 4;

    float An[4], a[4], bb[4];
#pragma unroll
    for (int k = 0; k < 4; ++k) {
        An[k] = -__expf(A_log[d * DS + n0 + k]);
        a[k] = 1.f; bb[k] = 0.f;
    }
    const size_t r0 = (size_t)b * SEQLEN + (size_t)c * CH;
    for (int l = 0; l < CH; ++l) {
        const size_t row = r0 + l;
        float dtv = dt[row * DI + d];
        float xv  = xs[row * DI + d];
        float dtx = dtv * xv;
#pragma unroll
        for (int k = 0; k < 4; ++k) {
            float Bv = xdbl[row * XP + 48 + n0 + k];
            float dA = __expf(dtv * An[k]);
            a[k] *= dA;
            bb[k] = fmaf(dA, bb[k], dtx * Bv);
        }
    }
    float2* tp = trans + ((size_t)(b * NC + c) * DI + d) * DS + n0;
#pragma unroll
    for (int k = 0; k < 4; ++k) tp[k] = make_float2(a[k], bb[k]);
}

__global__ __launch_bounds__(256)
void scan_chunk_b(float2* __restrict__ trans)
{
    const int idx = blockIdx.x * 256 + threadIdx.x;
    const int b = idx / (DI * DS);
    const int dn = idx % (DI * DS);
    float2* tp = trans + (size_t)b * NC * DI * DS + dn;
    float h = 0.f;
    for (int c = 0; c < NC; ++c) {
        float2 ab = tp[(size_t)c * DI * DS];
        tp[(size_t)c * DI * DS].y = h;
        h = fmaf(ab.x, h, ab.y);
    }
}

__global__ __launch_bounds__(256)
void scan_chunk_c(float* xz, const float* __restrict__ xs,
                  const float* __restrict__ dt, const float* __restrict__ xdbl,
                  const float* __restrict__ A_log, const float* __restrict__ Dvec,
                  const float2* __restrict__ trans)
{
    const int q = threadIdx.x & 3;
    const int dloc = threadIdx.x >> 2;
    const int d = blockIdx.x * 64 + dloc;
    const int c = blockIdx.y;
    const int b = blockIdx.z;
    const int n0 = q * 4;

    float An[4], h[4];
    const float2* tp = trans + ((size_t)(b * NC + c) * DI + d) * DS + n0;
#pragma unroll
    for (int k = 0; k < 4; ++k) {
        An[k] = -__expf(A_log[d * DS + n0 + k]);
        h[k] = tp[k].y;
    }
    const float Dd = Dvec[d];
    const size_t r0 = (size_t)b * SEQLEN + (size_t)c * CH;
    for (int l = 0; l < CH; ++l) {
        const size_t row = r0 + l;
        float dtv = dt[row * DI + d];
        float xv  = xs[row * DI + d];
        float dtx = dtv * xv;
        float p = 0.f;
#pragma unroll
        for (int k = 0; k < 4; ++k) {
            float Bv = xdbl[row * XP + 48 + n0 + k];
            float Cv = xdbl[row * XP + 64 + n0 + k];
            float dA = __expf(dtv * An[k]);
            h[k] = fmaf(dA, h[k], dtx * Bv);
            p = fmaf(h[k], Cv, p);
        }
        p += __shfl_xor(p, 1, 4);
        p += __shfl_xor(p, 2, 4);
        if (q == 0) {
            float zv = xz[row * XZC + DI + d];
            xz[row * XZC + d] = (p + xv * Dd) * siluf(zv);
        }
    }
}

extern "C" void kernel_launch(void* const* d_in, const int* in_sizes, int n_in,
                              void* d_out, int out_size, void* d_ws, size_t ws_size,
                              hipStream_t stream)
{
    const float* hidden    = (const float*)d_in[0];
    const float* query     = (const float*)d_in[1];
    const float* in_proj_w = (const float*)d_in[2];
    const float* conv_w    = (const float*)d_in[3];
    const float* conv_b    = (const float*)d_in[4];
    const float* x_proj_w  = (const float*)d_in[5];
    const float* dt_proj_w = (const float*)d_in[6];
    const float* dt_proj_b = (const float*)d_in[7];
    const float* A_log     = (const float*)d_in[8];
    const float* Dvec      = (const float*)d_in[9];
    const float* query_w   = (const float*)d_in[10];
    const float* query_b   = (const float*)d_in[11];
    const float* out_proj_w= (const float*)d_in[12];
    float* out = (float*)d_out;

    char* p = (char*)d_ws;
    float* xz   = (float*)p;  p += (size_t)M * XZC * 4;       // 50.3 MB
    float* xs   = (float*)p;  p += (size_t)M * DI * 4;        // 25.2 MB
    float* dtb  = (float*)p;  p += (size_t)M * DI * 4;        // 25.2 MB
    float* xdbl = (float*)p;  p += (size_t)M * XP * 4;        // 1.3 MB
    float2* trans = (float2*)p; p += (size_t)BATCH * NC * DI * DS * 8;  // 12.6 MB
    unsigned short* hb  = (unsigned short*)p; p += (size_t)M * DM * 2;      // 6.3 MB
    unsigned short* qb  = (unsigned short*)p; p += (size_t)M * DM * 2;      // 6.3 MB
    unsigned short* ygb = (unsigned short*)p; p += (size_t)M * DI * 2;      // 12.6 MB
    unsigned short* wib = (unsigned short*)p; p += (size_t)XZC * DM * 2;    // 4.7 MB
    unsigned short* wqb = (unsigned short*)p; p += (size_t)DI * DM * 2;     // 2.4 MB
    unsigned short* wob = (unsigned short*)p; p += (size_t)DM * DI * 2;     // 2.4 MB
    // x_proj split-K partials alias the ygb region (ygb written later, step 6):
    // KS * M * XP * 4 = 10.5 MB <= 12.6 MB
    float* xpart = (float*)ygb;

    dim3 blk(256);

    // 0. casts to bf16 (2 launches)
    cast_bf16_2<<<dim3((M * DM / 4 + 255) / 256, 2), blk, 0, stream>>>(
        hidden, hb, query, qb, M * DM / 4);
    {
        int n0 = XZC * DM / 4, n1 = DI * DM / 4, n2 = DM * DI / 4;
        cast_bf16_3<<<(n0 + n1 + n2 + 255) / 256, blk, 0, stream>>>(
            in_proj_w, wib, n0, query_w, wqb, n1, out_proj_w, wob, n2);
    }

    // 1. in_proj (bf16 MFMA): xz = hidden @ in_proj_w^T   (4096 x 3072, K=768)
    gemm_bf16<0><<<dim3(XZC / 128, M / 128), blk, 0, stream>>>(
        hb, DM, wib, DM, DM, xz, nullptr, XZC, nullptr, nullptr, 0);

    // 2. causal depthwise conv + silu -> xs
    conv_silu<<<(M * DI + 255) / 256, blk, 0, stream>>>(xz, conv_w, conv_b, xs);

    // 3. x_proj (fp32, deterministic split-K): partials then reduce
    gemm_nt<4><<<dim3((XP + 63) / 64, M / 64, KS), blk, 0, stream>>>(
        xs, DI, x_proj_w, DI, xpart, XP, XP, DI, DI / KS, nullptr);
    reduce_xp<<<(M * XP / 4 + 255) / 256, blk, 0, stream>>>(xpart, xdbl, M * XP / 4);

    // 4. dt_proj + softplus (fp32)                        (4096 x 1536, K=48)
    gemm_nt<1><<<dim3(DI / 64, M / 64, 1), blk, 0, stream>>>(
        xdbl, XP, dt_proj_w, 48, dtb, DI, DI, 48, 48, dt_proj_b);

    // 5. chunk-parallel selective scan -> y into xz[:, :1536]
    scan_chunk_a<<<dim3(DI / 64, NC, BATCH), blk, 0, stream>>>(dtb, xs, xdbl, A_log, trans);
    scan_chunk_b<<<(BATCH * DI * DS) / 256, blk, 0, stream>>>(trans);
    scan_chunk_c<<<dim3(DI / 64, NC, BATCH), blk, 0, stream>>>(xz, xs, dtb, xdbl, A_log, Dvec, trans);

    // 6. query gate (bf16 MFMA, EPI2): ygb = bf16( y * silu(query@query_w^T + qb) )
    gemm_bf16<2><<<dim3(DI / 128, M / 128), blk, 0, stream>>>(
        qb, DM, wqb, DM, DM, nullptr, ygb, DI, query_b, xz, XZC);

    // 7. out_proj (bf16 MFMA): out = ygb @ out_proj_w^T   (4096 x 768, K=1536)
    gemm_bf16<0><<<dim3(DM / 128, M / 128), blk, 0, stream>>>(
        ygb, DI, wob, DI, DI, out, nullptr, DM, nullptr, nullptr, 0);
}